// Round 7
// baseline (450.860 us; speedup 1.0000x reference)
//
#include <hip/hip_runtime.h>
#include <math.h>

#define NN 16384
#define KK 16
#define CAP 1024        // per-wave candidate buffer (u64 keys)
#define SW 4            // scan waves per block (1 row each)
#define RPB 4           // rows per block

typedef float f32x4 __attribute__((ext_vector_type(4)));
typedef unsigned long long u64;

// ---------- pack nodes into SoA float4 {x,y,z,sq} (reference arithmetic) ----
__global__ void prep_kernel(const float* __restrict__ nodes,
                            float4* __restrict__ pts) {
#pragma clang fp contract(off)
    const int i = blockIdx.x * blockDim.x + threadIdx.x;
    if (i < NN) {
        const float x = nodes[3 * i + 0];
        const float y = nodes[3 * i + 1];
        const float z = nodes[3 * i + 2];
        pts[i] = make_float4(x, y, z, (x * x + y * y) + z * z);
    }
}

// Verified distributed-sorted-list insert (identical to r1-r6) — fallback only.
__device__ __forceinline__ bool lexless(float da, int ia, float db, int ib) {
    return (da < db) || ((da == db) && (ia < ib));
}

__device__ __forceinline__ void insert_tile(bool rough, float d2, int j,
                                            float& ld, int& li,
                                            float& td, int& ti, float& td2u,
                                            int lane) {
#pragma clang fp contract(off)
    if (!__any(rough)) return;
    float dist = INFINITY;
    if (rough) dist = sqrtf(fmaxf(d2, 0.0f));
    bool done = false;
    while (true) {
        const bool pass = (!done) && rough && lexless(dist, j, td, ti);
        const unsigned long long m = __ballot(pass);
        if (m == 0ull) break;
        const int src = __ffsll(m) - 1;
        const float dc = __shfl(dist, src);
        const int   ic = __shfl(j, src);
        if (lane == src) done = true;
        const bool gt = lexless(dc, ic, ld, li);
        const unsigned long long gm = __ballot(gt);
        const int p = __ffsll(gm) - 1;
        const float pd = __shfl_up(ld, 1);
        const int   pi = __shfl_up(li, 1);
        if (gt) {
            if (lane == p) { ld = dc; li = ic; }
            else           { ld = pd; li = pi; }
        }
        td = __shfl(ld, 16);
        ti = __shfl(li, 16);
        td2u = td * td * 1.000001f;
    }
}

// Append one tile's passers to the per-wave LDS buffer (compacted).
#define APPEND(D2V, JV) do {                                                   \
    const bool pass_ = (D2V) <= thr;                                           \
    const u64 mask_ = __ballot(pass_);                                         \
    if (mask_) {                                                               \
        const int pos_ = count + (int)__popcll(mask_ & ((1ull<<lane)-1ull));   \
        if (pass_ && pos_ < CAP)                                               \
            mybuf[pos_] = (((u64)__float_as_uint(fmaxf((D2V),0.0f)))<<32)      \
                          | (unsigned)(JV);                                    \
        const int nc_ = count + (int)__popcll(mask_);                          \
        ovf = ovf || (nc_ > CAP);                                              \
        count = nc_ > CAP ? CAP : nc_;                                         \
    } } while(0)

// ---------- main kernel: 4 scan waves (1 row each) + 1 zero/ones wave -------
__global__ __launch_bounds__(320) void knn_main(const float4* __restrict__ pts,
                                                float* __restrict__ out) {
#pragma clang fp contract(off)
    const int lane = threadIdx.x & 63;
    const int wid  = threadIdx.x >> 6;
    const int rowBase = blockIdx.x * RPB;

    __shared__ u64 buf[SW][CAP];    // 32 KB: per-wave candidate keys
    __shared__ u64 sel[SW][24];     // top-24 by (cd2, idx)
    __shared__ u64 sel2[SW][24];    // repacked (distbits, idx) for lex rank
    __shared__ int nb[SW][KK];

    if (wid == SW) {
        // Fill wave: NT-stream zeros for this block's 4 rows (256 KB).
        f32x4* ob = (f32x4*)(out + (size_t)rowBase * NN);
        const f32x4 z4 = {0.f, 0.f, 0.f, 0.f};
#pragma unroll 8
        for (int k = 0; k < RPB * (NN / 4) / 64; ++k)
            __builtin_nontemporal_store(z4, ob + k * 64 + lane);
        asm volatile("s_waitcnt vmcnt(0)" ::: "memory");
    } else {
        const int row = rowBase + wid;
        const float4 p = pts[row];
        const float xi = p.x, yi = p.y, zi = p.z, sqi = p.w;
        u64* mybuf = buf[wid];

        float thr = INFINITY, runmin = INFINITY;
        int count = 0; bool ovf = false;

        float4 q0 = pts[lane];
        float4 q1 = pts[64 + lane];
        float4 q2 = pts[128 + lane];
        float4 q3 = pts[192 + lane];

        for (int t = 0; t < NN / 256; ++t) {
            const int base = t * 256;
            const int nxt = (t + 1 < NN / 256) ? base + 256 : base;
            const float4 n0 = pts[nxt + lane];
            const float4 n1 = pts[nxt + 64 + lane];
            const float4 n2 = pts[nxt + 128 + lane];
            const float4 n3 = pts[nxt + 192 + lane];

            // Reference arithmetic: fma-chain dot, un-contracted d2.
            const float e0 = (sqi + q0.w) - 2.0f * fmaf(zi, q0.z, fmaf(yi, q0.y, xi * q0.x));
            const float e1 = (sqi + q1.w) - 2.0f * fmaf(zi, q1.z, fmaf(yi, q1.y, xi * q1.x));
            const float e2 = (sqi + q2.w) - 2.0f * fmaf(zi, q2.z, fmaf(yi, q2.y, xi * q2.x));
            const float e3 = (sqi + q3.w) - 2.0f * fmaf(zi, q3.z, fmaf(yi, q3.y, xi * q3.x));
            runmin = fminf(runmin, fminf(fminf(e0, e1), fminf(e2, e3)));

            APPEND(e0, base + lane);
            APPEND(e1, base + 64 + lane);
            APPEND(e2, base + 128 + lane);
            APPEND(e3, base + 192 + lane);

            // Conservative screen bound: max over 32 pair-mins >= 17th-smallest
            // (each pair contributes >=1 value <= bound -> >=32 <= bound >= 17).
            float pm = fminf(runmin, __shfl_xor(runmin, 1));
            float mx = pm;
            mx = fmaxf(mx, __shfl_xor(mx, 2));
            mx = fmaxf(mx, __shfl_xor(mx, 4));
            mx = fmaxf(mx, __shfl_xor(mx, 8));
            mx = fmaxf(mx, __shfl_xor(mx, 16));
            mx = fmaxf(mx, __shfl_xor(mx, 32));
            thr = fminf(thr, mx + fabsf(mx) * 1e-6f + 1e-30f);

            q0 = n0; q1 = n1; q2 = n2; q3 = n3;
        }

        if (!ovf) {
            // ---- batch select: top-24 by (cd2, idx) via 24 wave-min rounds ----
            u64 kk[16];
#pragma unroll
            for (int r = 0; r < 16; ++r) {
                const int s = r * 64 + lane;
                kk[r] = (s < count) ? mybuf[s] : ~0ull;
            }
            for (int c = 0; c < 24; ++c) {
                u64 m = kk[0];
#pragma unroll
                for (int r = 1; r < 16; ++r) m = kk[r] < m ? kk[r] : m;
#pragma unroll
                for (int sft = 1; sft <= 32; sft <<= 1) {
                    const u64 o = __shfl_xor(m, sft);
                    m = o < m ? o : m;
                }
                if (lane == 0) sel[wid][c] = m;
#pragma unroll
                for (int r = 0; r < 16; ++r) kk[r] = (kk[r] == m) ? ~0ull : kk[r];
            }
            // ---- exact lex-(dist, idx) rank among the 24 (ties by idx) ----
            if (lane < 24) {
                const u64 key = sel[wid][lane];
                const unsigned idxv = (unsigned)key;
                const float cd2 = __uint_as_float((unsigned)(key >> 32));
                const float dist = sqrtf(cd2);          // IEEE, matches reference
                sel2[wid][lane] = (((u64)__float_as_uint(dist)) << 32) | idxv;
            }
            asm volatile("s_waitcnt lgkmcnt(0)" ::: "memory");
            const u64 mine = (lane < 24) ? sel2[wid][lane] : ~0ull;
            int rank = 0;
            for (int m2 = 0; m2 < 24; ++m2)
                rank += (sel2[wid][m2] < mine) ? 1 : 0;
            if (lane < 24 && rank >= 1 && rank <= KK)
                nb[wid][rank - 1] = (int)(unsigned)mine;   // rank 0 = self, dropped
        } else {
            // ---- rare overflow fallback: verified streaming insert ----
            float ld = INFINITY; int li = 0x7fffffff;
            float td = INFINITY; int ti = 0x7fffffff; float td2u = INFINITY;
            for (int tt = 0; tt < NN / 64; ++tt) {
                const int j = tt * 64 + lane;
                const float4 q = pts[j];
                const float dd = (sqi + q.w) - 2.0f * fmaf(zi, q.z, fmaf(yi, q.y, xi * q.x));
                insert_tile(dd <= td2u, dd, j, ld, li, td, ti, td2u, lane);
            }
            if (lane >= 1 && lane <= KK) nb[wid][lane - 1] = li;
        }
    }

    __syncthreads();

    // Fill wave writes all 64 ones (4 rows x 16), ordered after its own
    // drained zero stores (same-wave ordering, r6-verified pattern).
    if (wid == SW) {
        const int r = lane >> 4;
        const int c = lane & 15;
        out[(size_t)(rowBase + r) * NN + nb[r][c]] = 1.0f;
    }
}

extern "C" void kernel_launch(void* const* d_in, const int* in_sizes, int n_in,
                              void* d_out, int out_size, void* d_ws, size_t ws_size,
                              hipStream_t stream) {
    const float* nodes = (const float*)d_in[0];
    float* out = (float*)d_out;
    (void)in_sizes; (void)n_in; (void)out_size; (void)ws_size;
    float4* pts = (float4*)d_ws;    // 256 KB scratch

    hipLaunchKernelGGL(prep_kernel, dim3(NN / 256), dim3(256), 0, stream,
                       nodes, pts);
    hipLaunchKernelGGL(knn_main, dim3(NN / RPB), dim3(320), 0, stream,
                       pts, out);
}